// Round 14
// baseline (141.987 us; speedup 1.0000x reference)
//
#include <hip/hip_runtime.h>
#include <hip/hip_bf16.h>
#include <stdint.h>

typedef unsigned short u16;
typedef unsigned int u32;
typedef __bf16 bf16x8 __attribute__((ext_vector_type(8)));
typedef float f32x4 __attribute__((ext_vector_type(4)));

// 1/sqrt(512) * log2(e) — folded into Wq at convert time
#define WQ_SCALE (0.044194173824159216f * 1.4426950408889634f)

#define FENCE __builtin_amdgcn_sched_barrier(0)
#define BAR() do { FENCE; __builtin_amdgcn_s_barrier(); FENCE; } while (0)
#define VMW(n) asm volatile("s_waitcnt vmcnt(" #n ")" ::: "memory")

__device__ __forceinline__ u16 f2bf(float f) {
  u32 u = __builtin_bit_cast(u32, f);
  u += 0x7FFFu + ((u >> 16) & 1u);
  return (u16)(u >> 16);
}

__device__ __forceinline__ void gload_lds16(const void* g, void* l) {
  __builtin_amdgcn_global_load_lds(
      (const __attribute__((address_space(1))) u32*)g,
      (__attribute__((address_space(3))) u32*)l, 16, 0, 0);
}

// ---------------- concat + f32->bf16 ----------------
__global__ void k_concat_bf16(const float* __restrict__ x, const float* __restrict__ y,
                              u16* __restrict__ xyb) {
  int tid = blockIdx.x * blockDim.x + threadIdx.x;
  int e = tid * 4;
  int s = e >> 9;
  int d = e & 511;
  int b = s >> 11, r = s & 2047;
  const float* src = (r < 1024) ? (x + ((size_t)(b * 1024 + r) * 512 + d))
                                : (y + ((size_t)(b * 1024 + (r - 1024)) * 512 + d));
  float4 v = *(const float4*)src;
  ushort4 o;
  o.x = f2bf(v.x); o.y = f2bf(v.y); o.z = f2bf(v.z); o.w = f2bf(v.w);
  *(ushort4*)(xyb + e) = o;
}

// weights: Wq (scaled by WQ_SCALE), Wk -> Wqkb stacked; Wv -> Wvb
__global__ void k_w_to_bf16(const float* __restrict__ Wq, const float* __restrict__ Wk,
                            const float* __restrict__ Wv,
                            u16* __restrict__ Wqkb, u16* __restrict__ Wvb) {
  int tid = blockIdx.x * blockDim.x + threadIdx.x;  // 196608 threads
  int which = tid >> 16;
  int e = (tid & 65535) * 4;
  const float* src = (which == 0) ? Wq : (which == 1) ? Wk : Wv;
  u16* dst = (which == 0) ? Wqkb : (which == 1) ? (Wqkb + 262144) : Wvb;
  float sc = (which == 0) ? WQ_SCALE : 1.0f;
  float4 v = *(const float4*)(src + e);
  ushort4 o;
  o.x = f2bf(v.x * sc); o.y = f2bf(v.y * sc);
  o.z = f2bf(v.z * sc); o.w = f2bf(v.w * sc);
  *(ushort4*)(dst + e) = o;
}

// ---------------- 8-phase counted-vmcnt GEMM: C = A * B^T ----------------
// BM=256, BK=64, 8 waves, 2 K-tiles per loop iteration (even tile -> slot0,
// odd -> slot1, no pointer swap). 4 quadrant-phases per tile in order
// (0,0),(0,1),(1,1),(1,0): B-halves die at ph+1, A-halves at ph+2 (both B
// fragment sets register-held). One half-tile staged per phase into
// just-freed LDS: ph0/1: s1.A0/A1 (tile T+1); ph2/3: s0.B0/B1 (T+2);
// ph4/5: s0.A0/A1 (T+2); ph6/7: s1.B0/B1 (T+3). Counted gates ONLY at
// ph3-end and ph7-end (vmcnt keeps 2 half-tiles in flight; never drains to
// 0 mid-loop). Last iteration: G1 = vmcnt(0) (coverage hole otherwise).
// LDS rows 128B XOR-swizzled via pre-swizzled global_load_lds source.
// EXPONLY: C = bf16(exp2(acc)) (log2e/sqrtD pre-folded into A upstream).
// PVL: l[m] = rowsum(A) via ones-operand MFMA; C = f32(acc / l).
// Second operand set (A2..split): independent GEMM for bid>=split.
template <int BN, int EXPONLY, int PVL, int OUTM>
__global__ __launch_bounds__(512, 2) void k_gemm8(
    const u16* A_, const u16* B_, void* Cv_,
    int lda, int ldb, int ldc,
    long long sA, long long sB, long long sC,
    int K, int batches, int mtiles, int ntiles,
    const u16* A2, const u16* B2, void* Cv2,
    int lda2, int ldb2, int ldc2, int mtiles2, int ntiles2, int split) {
  constexpr int NA = (BN == 256) ? 4 : 2;  // A frags per half (per wave)
  constexpr int M_rep = NA * 2;
  constexpr int WN = (BN == 256) ? 4 : 2;
  constexpr int A_BYTES = 256 * 128;       // 32 KB
  constexpr int B_BYTES = BN * 128;        // 32 / 16 KB
  constexpr int BUFB = A_BYTES + B_BYTES;
  constexpr int BH = (BN == 256) ? 16384 : 8192;  // B-half bytes

  __shared__ __align__(16) char lds[2 * BUFB];
  char* const s0 = lds;
  char* const s1 = lds + BUFB;

  int t = threadIdx.x;
  int lane = t & 63;
  int w = t >> 6;
  int wr = w / WN, wc = w % WN;

  const u16* A = A_;
  const u16* B = B_;
  void* Cv = Cv_;
  int bid = blockIdx.x;
  if (split && bid >= split) {
    bid -= split;
    A = A2; B = B2; Cv = Cv2;
    lda = lda2; ldb = ldb2; ldc = ldc2;
    mtiles = mtiles2; ntiles = ntiles2;
  }

  long long z = bid % batches;
  int t2 = bid / batches;
  int tx = t2 % mtiles, ty = t2 / mtiles;

  size_t rsA = (size_t)lda * 2, rsB = (size_t)ldb * 2;
  int srow = t >> 3;
  int scb = ((t & 7) * 16) ^ ((srow & 7) << 4);  // pre-swizzled source byte col

  const char* Abp = (const char*)(A + z * sA + (size_t)tx * 256 * lda) + scb;
  const char* Bbp = (const char*)(B + z * sB + (size_t)ty * BN * ldb) + scb;

  // stage one A-half (128 rows, 2 loads/thread) of tile kt into slot sb
  auto stA = [&](char* sb, int h, int kt) {
#pragma unroll
    for (int r = 0; r < 2; ++r)
      gload_lds16(Abp + (size_t)(h * 128 + r * 64 + srow) * rsA + (size_t)kt * 128,
                  sb + h * 16384 + r * 8192 + t * 16);
  };
  // stage one B-half (BN/2 rows; 2 loads BN=256, 1 load BN=128)
  auto stB = [&](char* sb, int h, int kt) {
    if constexpr (BN == 256) {
#pragma unroll
      for (int r = 0; r < 2; ++r)
        gload_lds16(Bbp + (size_t)(h * 128 + r * 64 + srow) * rsB + (size_t)kt * 128,
                    sb + A_BYTES + h * 16384 + r * 8192 + t * 16);
    } else {
      gload_lds16(Bbp + (size_t)(h * 64 + srow) * rsB + (size_t)kt * 128,
                  sb + A_BYTES + h * BH + t * 16);
    }
  };

  int axor = (lane & 7) << 4;
  int arow0 = wr * (M_rep * 16) + (lane & 15);
  int brow0 = wc * 64 + (lane & 15);
  int kb0 = (lane >> 4) * 16;

  bf16x8 afr[NA][2], bfr0[2][2], bfr1[2][2];
  f32x4 acc[M_rep][4] = {};
  f32x4 acc_l[M_rep] = {};
  bf16x8 ones;
#pragma unroll
  for (int j = 0; j < 8; ++j) ones[j] = (__bf16)1.0f;

  auto rdA = [&](const char* sb, int mq) {
#pragma unroll
    for (int i = 0; i < NA; ++i)
#pragma unroll
      for (int kk = 0; kk < 2; ++kk)
        afr[i][kk] = *(const bf16x8*)(sb + (arow0 + mq * (NA * 16) + i * 16) * 128 +
                                      ((kb0 + kk * 64) ^ axor));
  };
  auto rdB = [&](const char* sb, bf16x8 (&bf)[2][2], int nq) {
#pragma unroll
    for (int j = 0; j < 2; ++j)
#pragma unroll
      for (int kk = 0; kk < 2; ++kk)
        bf[j][kk] = *(const bf16x8*)(sb + A_BYTES + (brow0 + nq * 32 + j * 16) * 128 +
                                     ((kb0 + kk * 64) ^ axor));
  };

#define MMA(MQ, NQ, BF, ONES) do {                                            \
    __builtin_amdgcn_s_setprio(1);                                            \
    _Pragma("unroll") for (int i = 0; i < NA; ++i)                            \
    _Pragma("unroll") for (int j = 0; j < 2; ++j)                             \
    _Pragma("unroll") for (int kk = 0; kk < 2; ++kk)                          \
      acc[(MQ) * NA + i][(NQ) * 2 + j] = __builtin_amdgcn_mfma_f32_16x16x32_bf16( \
          afr[i][kk], BF[j][kk], acc[(MQ) * NA + i][(NQ) * 2 + j], 0, 0, 0);  \
    if constexpr (PVL) { if (ONES) {                                          \
      _Pragma("unroll") for (int i = 0; i < NA; ++i)                          \
      _Pragma("unroll") for (int kk = 0; kk < 2; ++kk)                        \
        acc_l[(MQ) * NA + i] = __builtin_amdgcn_mfma_f32_16x16x32_bf16(       \
            afr[i][kk], ones, acc_l[(MQ) * NA + i], 0, 0, 0); } }             \
    __builtin_amdgcn_s_setprio(0);                                            \
  } while (0)

  int NT = K >> 6, NI = NT >> 1;

  // prologue: tile0 fully + tile1's B halves (tile1's A staged at it0 ph0/ph1)
  stA(s0, 0, 0); stA(s0, 1, 0); stB(s0, 0, 0); stB(s0, 1, 0);
  stB(s1, 0, 1); stB(s1, 1, 1);
  if constexpr (BN == 256) VMW(4); else VMW(2);
  BAR();

  for (int it = 0; it < NI; ++it) {
    int T = 2 * it;
    bool last = (it == NI - 1);
    bool st0 = (T + 2 < NT);
    bool st1 = (T + 3 < NT);

    // ---- tile T (slot0) ----
    // ph0: quadrant (0,0)
    rdA(s0, 0); rdB(s0, bfr0, 0);
    stA(s1, 0, T + 1);
    BAR(); MMA(0, 0, bfr0, true); BAR();
    // ph1: (0,1)
    rdB(s0, bfr1, 1);
    stA(s1, 1, T + 1);
    BAR(); MMA(0, 1, bfr1, false); BAR();
    // ph2: (1,1)
    rdA(s0, 1);
    if (st0) { stB(s0, 0, T + 2); if constexpr (BN == 128) stB(s0, 1, T + 2); }
    BAR(); MMA(1, 1, bfr1, true); BAR();
    // ph3: (1,0) + gate G1
    if (st0) { if constexpr (BN == 256) stB(s0, 1, T + 2); else stA(s0, 0, T + 2); }
    BAR(); MMA(1, 0, bfr0, false);
    if (last) { VMW(0); } else { VMW(4); }
    BAR();

    // ---- tile T+1 (slot1) ----
    // ph4: (0,0)
    rdA(s1, 0); rdB(s1, bfr0, 0);
    if (st0) { if constexpr (BN == 256) stA(s0, 0, T + 2); else stA(s0, 1, T + 2); }
    BAR(); MMA(0, 0, bfr0, true); BAR();
    // ph5: (0,1)
    rdB(s1, bfr1, 1);
    if (st0) { if constexpr (BN == 256) stA(s0, 1, T + 2); }
    BAR(); MMA(0, 1, bfr1, false); BAR();
    // ph6: (1,1)
    rdA(s1, 1);
    if (st1) { stB(s1, 0, T + 3); if constexpr (BN == 128) stB(s1, 1, T + 3); }
    BAR(); MMA(1, 1, bfr1, true); BAR();
    // ph7: (1,0) + gate G2
    if (st1) { if constexpr (BN == 256) stB(s1, 1, T + 3); }
    BAR(); MMA(1, 0, bfr0, false);
    if (!last) { if constexpr (BN == 256) VMW(4); else VMW(2); }
    BAR();
  }
#undef MMA

  // ---------------- epilogue ----------------
#pragma unroll
  for (int m = 0; m < M_rep; ++m) {
    int grow = tx * 256 + wr * (M_rep * 16) + m * 16 + ((lane >> 4) << 2);
#pragma unroll
    for (int r = 0; r < 4; ++r) {
      float linv_v = 1.0f;
      if constexpr (PVL) linv_v = 1.0f / acc_l[m][r];
#pragma unroll
      for (int n = 0; n < 4; ++n) {
        int col = ty * BN + wc * 64 + n * 16 + (lane & 15);
        size_t idx = (size_t)(z * sC) + (size_t)(grow + r) * ldc + col;
        if constexpr (EXPONLY) {
          ((u16*)Cv)[idx] = f2bf(exp2f(acc[m][n][r]));
        } else if constexpr (OUTM == 0) {
          ((u16*)Cv)[idx] = f2bf(acc[m][n][r]);
        } else {
          ((float*)Cv)[idx] = acc[m][n][r] * linv_v;
        }
      }
    }
  }
}

extern "C" void kernel_launch(void* const* d_in, const int* in_sizes, int n_in,
                              void* d_out, int out_size, void* d_ws, size_t ws_size,
                              hipStream_t stream) {
  const float* x = (const float*)d_in[0];
  const float* y = (const float*)d_in[1];
  const float* Wq = (const float*)d_in[2];
  const float* Wk = (const float*)d_in[3];
  const float* Wv = (const float*)d_in[4];
  float* out = (float*)d_out;

  char* p = (char*)d_ws;
  u16* QKb = (u16*)p; p += (size_t)16384 * 1024 * 2;  // Q (pre-scaled) | K
  u16* VTb = (u16*)p; p += (size_t)16384 * 512 * 2;   // V^T bf16 [512][16384]
  u16* Wqkb = (u16*)p; p += (size_t)1024 * 512 * 2;   // [scaled Wq; Wk]
  u16* Wvb = (u16*)p; p += (size_t)512 * 512 * 2;
  size_t base = (size_t)(p - (char*)d_ws);
  u16* xyb = (u16*)p;   // concat bf16; dead after merged projection
  u16* Sb = (u16*)p;    // P (bf16) aliases xyb

  int nc = (ws_size >= base + (size_t)16384 * 2048 * 2) ? 1 : 2;
  int mrows = 2048 / nc;
  int mt = mrows / 256;

  // converts
  k_concat_bf16<<<8192, 256, 0, stream>>>(x, y, xyb);
  k_w_to_bf16<<<768, 256, 0, stream>>>(Wq, Wk, Wv, Wqkb, Wvb);

  // merged projections (768 blocks):
  //   blocks 0-511:  QK = xy @ [cWq;Wk]^T -> QKb [16384][1024]
  //   blocks 512-767: VT = Wv @ xy^T      -> VTb [512][16384]
  k_gemm8<128, 0, 0, 0><<<768, 512, 0, stream>>>(
      xyb, Wqkb, QKb, 512, 512, 1024, 0, 0, 0, 512, 1, 64, 8,
      Wvb, xyb, VTb, 512, 512, 16384, 2, 128, 512);

  for (int c = 0; c < nc; ++c) {
    const u16* Qc = QKb + (size_t)c * mrows * 1024;
    // P = exp2(Q K^T) (bf16 out; log2e/sqrtD folded into Q)
    k_gemm8<256, 1, 0, 0><<<8 * mt * 8, 512, 0, stream>>>(
        Qc, QKb + 512, Sb, 1024, 1024, 2048,
        (long long)2048 * 1024, (long long)2048 * 1024, (long long)mrows * 2048,
        512, 8, mt, 8,
        nullptr, nullptr, nullptr, 0, 0, 0, 0, 0, 0);
    // O = (P @ VT^T) / rowsum(P)  (l via ones-MFMA)
    k_gemm8<128, 0, 1, 2><<<8 * mt * 4, 512, 0, stream>>>(
        Sb, VTb, out + (size_t)c * mrows * 512, 2048, 16384, 512,
        (long long)mrows * 2048, (long long)2048, (long long)2048 * 512,
        2048, 8, mt, 4,
        nullptr, nullptr, nullptr, 0, 0, 0, 0, 0, 0);
  }
}